// Round 16
// baseline (73.916 us; speedup 1.0000x reference)
//
#include <hip/hip_runtime.h>
#include <hip/hip_bf16.h>

#define BB 16
#define TT 2048
#define DIMC 512
#define HEADH 64

typedef __attribute__((ext_vector_type(8))) short short8v;   // 8 bf16 (4 VGPRs)
typedef __attribute__((ext_vector_type(4))) float f32x4;     // 16x16 MFMA C/D
typedef __attribute__((ext_vector_type(16))) float f32x16;   // 32x32 MFMA C/D

static __device__ __forceinline__ unsigned short f2bf(float f) {
    __hip_bfloat16 h = __float2bfloat16(f);          // RNE, native path
    unsigned short u;
    __builtin_memcpy(&u, &h, 2);
    return u;
}
static __device__ __forceinline__ unsigned int packbf(float lo, float hi) {
    float2 f2; f2.x = lo; f2.y = hi;
    __hip_bfloat162 h2 = __float22bfloat162_rn(f2);
    unsigned int u;
    __builtin_memcpy(&u, &h2, 4);
    return u;
}
// raw v_exp_f32 (log2 domain; args <= 0, flush-to-zero is fine for softmax)
#define EXP2R __builtin_amdgcn_exp2f
// async global->LDS, 16B per lane; LDS dest = wave-uniform base + lane*16
static __device__ __forceinline__ void async_copy16(void* lds, const void* g) {
    __builtin_amdgcn_global_load_lds(
        (const __attribute__((address_space(1))) unsigned char*)g,
        (__attribute__((address_space(3))) unsigned char*)lds, 16, 0, 0);
}

union bfrag {
    unsigned int u[4];
    short8v v;
};

// ---------------- Kernel 0: W f32 -> bf16, concat [q|k|v] rows -------------
__global__ __launch_bounds__(256) void wcvt_kernel(
    const float* __restrict__ Wq, const float* __restrict__ Wk,
    const float* __restrict__ Wv, unsigned short* __restrict__ wb)
{
    const int idx = blockIdx.x * 256 + threadIdx.x;   // 12288 threads x 8 elems
    const int e   = idx << 3;
    const int row = e >> 9, col = e & 511;
    const float* src = (row < 64) ? Wq : (row < 128) ? Wk : Wv;
    const float* p = src + (size_t)(row & 63) * DIMC + col;
    float4 a = *(const float4*)p;
    float4 b = *(const float4*)(p + 4);
    uint4 o;
    o.x = packbf(a.x, a.y); o.y = packbf(a.z, a.w);
    o.z = packbf(b.x, b.y); o.w = packbf(b.z, b.w);
    *(uint4*)(wb + e) = o;
}

// ---------------- Kernel A: MFMA QKV projection + rotary, LDS-staged --------
// (exact r13 version: measured ~24us)
__global__ __launch_bounds__(256, 2) void qkv_mfma_kernel(
    const float* __restrict__ x,
    const unsigned short* __restrict__ wb,
    const float* __restrict__ fxr, const float* __restrict__ fxi,
    const float* __restrict__ fyr, const float* __restrict__ fyi,
    unsigned short* __restrict__ qo, unsigned short* __restrict__ ko,
    unsigned short* __restrict__ vt)
{
    __shared__ unsigned char xlds[16384];     // [2][64][32] f32, dbuf

    const int tid = threadIdx.x;
    const int w   = tid >> 6;                 // wave -> h-tile triple
    const int l   = tid & 63;
    const int q   = l & 15;
    const int g   = l >> 4;
    const int t0  = blockIdx.x << 6;          // 64 t-rows per block

    f32x4 acc[3][4];
    #pragma unroll
    for (int j = 0; j < 3; ++j)
        #pragma unroll
        for (int tt = 0; tt < 4; ++tt) acc[j][tt] = (f32x4){0.f, 0.f, 0.f, 0.f};

    const unsigned short* wp0 = wb + ((size_t)((3 * w + 0) * 16 + q)) * DIMC + 8 * g;
    const unsigned short* wp1 = wb + ((size_t)((3 * w + 1) * 16 + q)) * DIMC + 8 * g;
    const unsigned short* wp2 = wb + ((size_t)((3 * w + 2) * 16 + q)) * DIMC + 8 * g;

    const int rl = l >> 3;                    // 0..7 row-in-call
    const int cb = (l & 7) ^ rl;              // source col-block (involution)
    const float* xsrc0 = x + (size_t)(t0 + 16 * w + 0 + rl) * DIMC + 4 * cb;
    const float* xsrc1 = x + (size_t)(t0 + 16 * w + 8 + rl) * DIMC + 4 * cb;
    unsigned char* xdst0 = xlds + (16 * w + 0) * 128;   // wave-uniform bases
    unsigned char* xdst1 = xlds + (16 * w + 8) * 128;

#define STAGE_X(bufsel, k0) do {                                              \
        async_copy16(xdst0 + (bufsel) * 8192, xsrc0 + (k0));                  \
        async_copy16(xdst1 + (bufsel) * 8192, xsrc1 + (k0));                  \
    } while (0)

    STAGE_X(0, 0);
    __syncthreads();

    int cur = 0;
    for (int it = 0; it < 16; ++it) {
        const int k0 = it << 5;
        if (it < 15) STAGE_X(cur ^ 1, k0 + 32);

        short8v wf0 = *(const short8v*)(wp0 + k0);
        short8v wf1 = *(const short8v*)(wp1 + k0);
        short8v wf2 = *(const short8v*)(wp2 + k0);

        const unsigned char* xb = xlds + cur * 8192;
        #pragma unroll
        for (int tt = 0; tt < 4; ++tt) {
            const int rr = tt * 16 + q;
            const int s0 = (2 * g)     ^ (q & 7);
            const int s1 = (2 * g + 1) ^ (q & 7);
            float4 f0 = *(const float4*)(xb + rr * 128 + s0 * 16);
            float4 f1 = *(const float4*)(xb + rr * 128 + s1 * 16);
            bfrag xv;
            xv.u[0] = packbf(f0.x, f0.y); xv.u[1] = packbf(f0.z, f0.w);
            xv.u[2] = packbf(f1.x, f1.y); xv.u[3] = packbf(f1.z, f1.w);
            acc[0][tt] = __builtin_amdgcn_mfma_f32_16x16x32_bf16(wf0, xv.v, acc[0][tt], 0, 0, 0);
            acc[1][tt] = __builtin_amdgcn_mfma_f32_16x16x32_bf16(wf1, xv.v, acc[1][tt], 0, 0, 0);
            acc[2][tt] = __builtin_amdgcn_mfma_f32_16x16x32_bf16(wf2, xv.v, acc[2][tt], 0, 0, 0);
        }

        __syncthreads();                      // nxt resident; cur reads done
        cur ^= 1;
    }

    const float qscale = 1.4426950408889634f / 22.627416997969522f; // log2e/sqrt(512)
    #pragma unroll
    for (int j = 0; j < 3; ++j) {
        const int gt   = 3 * w + j;           // global h-tile 0..11
        const int mat  = gt >> 2;             // 0=q, 1=k, 2=v
        const int hbase = (gt & 3) * 16 + 4 * g;
        #pragma unroll
        for (int tt = 0; tt < 4; ++tt) {
            const int trow = t0 + tt * 16 + q;
            const int tl   = trow & (TT - 1);
            if (mat == 2) {
                const int b = trow >> 11;
                #pragma unroll
                for (int r = 0; r < 4; ++r)
                    vt[((size_t)(b * HEADH) + hbase + r) * TT + tl] = f2bf(acc[j][tt][r]);
            } else {
                const float sc = (mat == 0) ? qscale : 1.f;
                unsigned short* dst = ((mat == 0) ? qo : ko) + (size_t)trow * HEADH;
                const int half = hbase >> 5;
                const float* frt = half ? fyr : fxr;
                const float* fit = half ? fyi : fxi;
                const int pi0 = (hbase & 31) >> 1;
                float fr0 = frt[tl * 16 + pi0],     fi0 = fit[tl * 16 + pi0];
                float fr1 = frt[tl * 16 + pi0 + 1], fi1 = fit[tl * 16 + pi0 + 1];
                float e0 = acc[j][tt][0] * fr0 - acc[j][tt][1] * fi0;
                float e1 = acc[j][tt][0] * fi0 + acc[j][tt][1] * fr0;
                float e2 = acc[j][tt][2] * fr1 - acc[j][tt][3] * fi1;
                float e3 = acc[j][tt][2] * fi1 + acc[j][tt][3] * fr1;
                uint2 ow;
                ow.x = packbf(e0 * sc, e1 * sc);
                ow.y = packbf(e2 * sc, e3 * sc);
                *(uint2*)(dst + hbase) = ow;
            }
        }
    }
#undef STAGE_X
}

// ---------------- Kernel B: MFMA flash attention, 32x32 MFMA ----------------
// Round 16: r15 structure with the P-exchange rebuilt on verified-semantics
// primitives: 8x __shfl_xor(.,32) + selects replace the 4 v_permlane32_swap
// asm ops (r15's absmax 0.53 is consistent with a reversed swap direction;
// every other mapping re-derived + QK/PV proven robust to the A/B slot-map
// ambiguity since both operands share the same map).
// C-layout (m74/m101): col=l&31 (q), row(kv) = (r&3)+8*(r>>2)+4*(l>>5).
// Lane words: W0={4g5,4g5+1} W1={4g5+2,4g5+3} W2={8+4g5,9+4g5} W3={10+4g5,..}
// PV B-frag needs word_w = kv {8g5+2w,8g5+2w+1}:
//   pb0 = [g5?X2:W0, g5?X3:W1, g5?W2:X0, g5?W3:X1]   (X = shfl_xor 32)
//   pb1 = [g5?X6:W4, g5?X7:W5, g5?W6:X4, g5?W7:X5]
__global__ __launch_bounds__(512, 4) void attn_mfma_kernel(
    const unsigned short* __restrict__ qws,   // [b][t][64] bf16, pre-scaled
    const unsigned short* __restrict__ kws,   // [b][t][64] bf16
    const unsigned short* __restrict__ vtw,   // [b][d][t]  bf16 (V^T)
    float* __restrict__ out)
{
    __shared__ unsigned char smem[67584];

    const int tid = threadIdx.x;
    const int w   = tid >> 6;                 // 0..7
    const int wq  = w & 1;                    // q-subtile (32 rows)
    const int h   = w >> 1;                   // kv quarter 0..3
    const int l   = tid & 63;
    const int q   = l & 31;                   // q-row in subtile / tile row
    const int g5  = l >> 5;
    const int b   = blockIdx.x >> 5;
    const int q0  = (blockIdx.x & 31) << 6;   // 64 q-rows per block
    const int qb  = q0 + 32 * wq;             // wave q base

    const int rl  = l >> 3;                   // K staging: row-in-call 0..7
    const int skl = (l & 7) ^ rl;             // K src col-block (involution)
    const int rl4 = l >> 2;                   // V staging: row-in-call 0..15
    const int svl = (l & 3) ^ (rl4 & 3);      // V src col-block (involution)

    const unsigned short* kbase = kws + (size_t)b * TT * HEADH;
    const unsigned short* vbase = vtw + (size_t)b * HEADH * TT;

    // K: quarter rows h*512 + kv0 + [0,32); wave wq stages rows 16wq..+15
    const unsigned short* ksrc = kbase + (size_t)(h * 512 + 16 * wq + rl) * HEADH + 8 * skl;
    // V^T: d-rows 32wq..+31, t-cols h*512 + kv0 + [0,32)
    const unsigned short* vsrc = vbase + (size_t)(32 * wq + rl4) * TT + h * 512 + 8 * svl;

#define STAGE_TILE(bufsel, kv)  do {                                          \
        unsigned char* kd = smem + h * 8192 + (bufsel) * 4096 + wq * 2048;    \
        async_copy16(kd,        ksrc + (size_t)(kv) * HEADH);                 \
        async_copy16(kd + 1024, ksrc + (size_t)((kv) + 8) * HEADH);           \
        unsigned char* vd = smem + 32768 + h * 8192 + (bufsel) * 4096 + wq * 2048; \
        async_copy16(vd,        vsrc + (kv));                                 \
        async_copy16(vd + 1024, vsrc + (kv) + 16 * TT);                       \
    } while (0)

    // Q fragments (B operand): qf[kc] = Q[qb+q][16kc + 8g5 + 0..7]
    short8v qf[4];
    {
        const unsigned short* qp = qws + ((size_t)(b * TT + qb + q)) * HEADH + 8 * g5;
        #pragma unroll
        for (int kc = 0; kc < 4; ++kc) qf[kc] = *(const short8v*)(qp + 16 * kc);
    }

    f32x16 oacc[2];
    #pragma unroll
    for (int db = 0; db < 2; ++db)
        #pragma unroll
        for (int r = 0; r < 16; ++r) oacc[db][r] = 0.f;
    float m = -1e30f, lsum = 0.f;

    STAGE_TILE(0, 0);
    __syncthreads();                          // tile 0 resident

    int cur = 0;
    for (int it = 0; it < 16; ++it) {
        const int kv0 = it << 5;              // offset within this quarter
        if (it < 15) STAGE_TILE(cur ^ 1, kv0 + 32);

        const unsigned char* kb = smem + h * 8192 + cur * 4096;
        const unsigned char* vb = smem + 32768 + h * 8192 + cur * 4096;

        // ---- QK^T: S^T(32kv x 32q) = K(32x64).Q^T, 4 chained k-steps ----
        f32x16 sacc;
        #pragma unroll
        for (int r = 0; r < 16; ++r) sacc[r] = 0.f;
        #pragma unroll
        for (int kc = 0; kc < 4; ++kc) {
            const short8v kA = *(const short8v*)(kb + q * 128 +
                                   (((2 * kc + g5) ^ (q & 7)) << 4));
            sacc = __builtin_amdgcn_mfma_f32_32x32x16_bf16(kA, qf[kc], sacc, 0, 0, 0);
        }

        // ---- online softmax: lane owns q-row qb+q; kv spread l / l+32 ----
        float t0a = fmaxf(fmaxf(sacc[0], sacc[1]),   fmaxf(sacc[2], sacc[3]));
        float t1a = fmaxf(fmaxf(sacc[4], sacc[5]),   fmaxf(sacc[6], sacc[7]));
        float t2a = fmaxf(fmaxf(sacc[8], sacc[9]),   fmaxf(sacc[10], sacc[11]));
        float t3a = fmaxf(fmaxf(sacc[12], sacc[13]), fmaxf(sacc[14], sacc[15]));
        float cmax = fmaxf(fmaxf(t0a, t1a), fmaxf(t2a, t3a));
        cmax = fmaxf(cmax, __shfl_xor(cmax, 32));
        const float mnew = fmaxf(m, cmax);

        float p[16];
        #pragma unroll
        for (int r = 0; r < 16; ++r) p[r] = EXP2R(sacc[r] - mnew);

        // lane-held C words: kv pairs {4g5,+1},{4g5+2,+3},{8+4g5,+1},{10+4g5,+1}, +16...
        unsigned int W0 = packbf(p[0],  p[1]),  W1 = packbf(p[2],  p[3]);
        unsigned int W2 = packbf(p[4],  p[5]),  W3 = packbf(p[6],  p[7]);
        unsigned int W4 = packbf(p[8],  p[9]),  W5 = packbf(p[10], p[11]);
        unsigned int W6 = packbf(p[12], p[13]), W7 = packbf(p[14], p[15]);

        // exchange with paired lane l^32 (verified primitive), then select
        const unsigned int X0 = __shfl_xor(W0, 32);
        const unsigned int X1 = __shfl_xor(W1, 32);
        const unsigned int X2 = __shfl_xor(W2, 32);
        const unsigned int X3 = __shfl_xor(W3, 32);
        const unsigned int X4 = __shfl_xor(W4, 32);
        const unsigned int X5 = __shfl_xor(W5, 32);
        const unsigned int X6 = __shfl_xor(W6, 32);
        const unsigned int X7 = __shfl_xor(W7, 32);
        bfrag pb0, pb1;
        pb0.u[0] = g5 ? X2 : W0;
        pb0.u[1] = g5 ? X3 : W1;
        pb0.u[2] = g5 ? W2 : X0;
        pb0.u[3] = g5 ? W3 : X1;
        pb1.u[0] = g5 ? X6 : W4;
        pb1.u[1] = g5 ? X7 : W5;
        pb1.u[2] = g5 ? W6 : X4;
        pb1.u[3] = g5 ? W7 : X5;

        const float sc = EXP2R(m - mnew);
        if (__any(cmax > m)) {
            #pragma unroll
            for (int db = 0; db < 2; ++db)
                #pragma unroll
                for (int r = 0; r < 16; ++r) oacc[db][r] *= sc;
        }

        // ---- PV: out^T(64d x 32q) += V^T(64 x 32kv).P^T(32kv x 32q) ----
        #pragma unroll
        for (int db = 0; db < 2; ++db) {
            const int d = 32 * db + q;
            const short8v vA0 = *(const short8v*)(vb + d * 64 + (((g5) ^ (d & 3)) << 4));
            oacc[db] = __builtin_amdgcn_mfma_f32_32x32x16_bf16(vA0, pb0.v, oacc[db], 0, 0, 0);
            const short8v vA1 = *(const short8v*)(vb + d * 64 + (((2 + g5) ^ (d & 3)) << 4));
            oacc[db] = __builtin_amdgcn_mfma_f32_32x32x16_bf16(vA1, pb1.v, oacc[db], 0, 0, 0);
        }

        // ---- psum off the critical path ----
        float psum = 0.f;
        #pragma unroll
        for (int r = 0; r < 16; ++r) psum += p[r];
        psum += __shfl_xor(psum, 32);
        lsum = lsum * sc + psum;
        m = mnew;

        __syncthreads();                      // nxt resident; cur reads done
        cur ^= 1;
    }

    // ---- 4-way combine of KV-quarter partials through LDS ----
    __syncthreads();                           // all staging/reads done
    float* o_f  = (float*)smem;                // [4][64][64] f32 = 64KB
    float* ml_f = (float*)(smem + 65536);      // [4][2][64]
    {
        const int qrow = 32 * wq + q;
        #pragma unroll
        for (int db = 0; db < 2; ++db)
            #pragma unroll
            for (int rq = 0; rq < 4; ++rq) {
                float4 v = make_float4(oacc[db][4 * rq], oacc[db][4 * rq + 1],
                                       oacc[db][4 * rq + 2], oacc[db][4 * rq + 3]);
                *(float4*)&o_f[(h * 64 + qrow) * 64 + 32 * db + 8 * rq + 4 * g5] = v;
            }
        if (l < 32) {
            ml_f[h * 128 + 32 * wq + l]      = m;
            ml_f[h * 128 + 64 + 32 * wq + l] = lsum;
        }
    }
    __syncthreads();

    const int cq = tid >> 3;                   // 0..63: q row
    const int ch = (tid & 7) << 3;             // 0..56: h group of 8
    float mh[4], lh[4];
    #pragma unroll
    for (int hh = 0; hh < 4; ++hh) {
        mh[hh] = ml_f[hh * 128 + cq];
        lh[hh] = ml_f[hh * 128 + 64 + cq];
    }
    const float M = fmaxf(fmaxf(mh[0], mh[1]), fmaxf(mh[2], mh[3]));
    float den = 0.f;
    float num[8];
    #pragma unroll
    for (int j = 0; j < 8; ++j) num[j] = 0.f;
    #pragma unroll
    for (int hh = 0; hh < 4; ++hh) {
        const float al = EXP2R(mh[hh] - M);
        den += al * lh[hh];
        const float* ov = &o_f[(hh * 64 + cq) * 64 + ch];
        float4 v0 = *(const float4*)(ov);
        float4 v1 = *(const float4*)(ov + 4);
        num[0] += al * v0.x; num[1] += al * v0.y;
        num[2] += al * v0.z; num[3] += al * v0.w;
        num[4] += al * v1.x; num[5] += al * v1.y;
        num[6] += al * v1.z; num[7] += al * v1.w;
    }
    const float inv = 1.f / den;
    float* op = out + ((size_t)(b * TT + q0 + cq)) * HEADH + ch;
    *(float4*)(op)     = make_float4(num[0] * inv, num[1] * inv, num[2] * inv, num[3] * inv);
    *(float4*)(op + 4) = make_float4(num[4] * inv, num[5] * inv, num[6] * inv, num[7] * inv);
#undef STAGE_TILE
}

extern "C" void kernel_launch(void* const* d_in, const int* in_sizes, int n_in,
                              void* d_out, int out_size, void* d_ws, size_t ws_size,
                              hipStream_t stream)
{
    const float* x   = (const float*)d_in[0];
    const float* Wq  = (const float*)d_in[1];
    const float* Wk  = (const float*)d_in[2];
    const float* Wv  = (const float*)d_in[3];
    const float* fxr = (const float*)d_in[4];
    const float* fxi = (const float*)d_in[5];
    const float* fyr = (const float*)d_in[6];
    const float* fyi = (const float*)d_in[7];
    float* out = (float*)d_out;

    unsigned short* qo = (unsigned short*)d_ws;                  // 4 MB
    unsigned short* ko = qo + (size_t)BB * TT * HEADH;           // 4 MB
    unsigned short* vt = ko + (size_t)BB * TT * HEADH;           // 4 MB
    unsigned short* wb = vt + (size_t)BB * TT * HEADH;           // 192 KB

    wcvt_kernel<<<48, 256, 0, stream>>>(Wq, Wk, Wv, wb);
    qkv_mfma_kernel<<<(BB * TT) / 64, 256, 0, stream>>>(x, wb, fxr, fxi, fyr, fyi,
                                                        qo, ko, vt);
    attn_mfma_kernel<<<BB * 32, 512, 0, stream>>>(qo, ko, vt, out);
}

// Round 17
// 65.463 us; speedup vs baseline: 1.1291x; 1.1291x over previous
//
#include <hip/hip_runtime.h>
#include <hip/hip_bf16.h>

#define BB 16
#define TT 2048
#define DIMC 512
#define HEADH 64

typedef __attribute__((ext_vector_type(8))) short short8v;   // 8 bf16 (4 VGPRs)
typedef __attribute__((ext_vector_type(4))) float f32x4;     // MFMA C/D

static __device__ __forceinline__ unsigned short f2bf(float f) {
    __hip_bfloat16 h = __float2bfloat16(f);          // RNE, native path
    unsigned short u;
    __builtin_memcpy(&u, &h, 2);
    return u;
}
static __device__ __forceinline__ unsigned int packbf(float lo, float hi) {
    float2 f2; f2.x = lo; f2.y = hi;
    __hip_bfloat162 h2 = __float22bfloat162_rn(f2);
    unsigned int u;
    __builtin_memcpy(&u, &h2, 4);
    return u;
}
// raw v_exp_f32 (log2 domain; args <= 0, flush-to-zero is fine for softmax)
#define EXP2R __builtin_amdgcn_exp2f
// async global->LDS, 16B per lane; LDS dest = wave-uniform base + lane*16
static __device__ __forceinline__ void async_copy16(void* lds, const void* g) {
    __builtin_amdgcn_global_load_lds(
        (const __attribute__((address_space(1))) unsigned char*)g,
        (__attribute__((address_space(3))) unsigned char*)lds, 16, 0, 0);
}

union bfrag {
    unsigned int u[4];
    short8v v;
};

// ---------------- Kernel 0: W f32 -> bf16, concat [q|k|v] rows -------------
__global__ __launch_bounds__(256) void wcvt_kernel(
    const float* __restrict__ Wq, const float* __restrict__ Wk,
    const float* __restrict__ Wv, unsigned short* __restrict__ wb)
{
    const int idx = blockIdx.x * 256 + threadIdx.x;   // 12288 threads x 8 elems
    const int e   = idx << 3;
    const int row = e >> 9, col = e & 511;
    const float* src = (row < 64) ? Wq : (row < 128) ? Wk : Wv;
    const float* p = src + (size_t)(row & 63) * DIMC + col;
    float4 a = *(const float4*)p;
    float4 b = *(const float4*)(p + 4);
    uint4 o;
    o.x = packbf(a.x, a.y); o.y = packbf(a.z, a.w);
    o.z = packbf(b.x, b.y); o.w = packbf(b.z, b.w);
    *(uint4*)(wb + e) = o;
}

// ---------------- Kernel A: MFMA QKV projection + rotary, LDS-staged --------
// (exact r13 version: measured ~24us)
__global__ __launch_bounds__(256, 2) void qkv_mfma_kernel(
    const float* __restrict__ x,
    const unsigned short* __restrict__ wb,
    const float* __restrict__ fxr, const float* __restrict__ fxi,
    const float* __restrict__ fyr, const float* __restrict__ fyi,
    unsigned short* __restrict__ qo, unsigned short* __restrict__ ko,
    unsigned short* __restrict__ vt)
{
    __shared__ unsigned char xlds[16384];     // [2][64][32] f32, dbuf

    const int tid = threadIdx.x;
    const int w   = tid >> 6;                 // wave -> h-tile triple
    const int l   = tid & 63;
    const int q   = l & 15;
    const int g   = l >> 4;
    const int t0  = blockIdx.x << 6;          // 64 t-rows per block

    f32x4 acc[3][4];
    #pragma unroll
    for (int j = 0; j < 3; ++j)
        #pragma unroll
        for (int tt = 0; tt < 4; ++tt) acc[j][tt] = (f32x4){0.f, 0.f, 0.f, 0.f};

    const unsigned short* wp0 = wb + ((size_t)((3 * w + 0) * 16 + q)) * DIMC + 8 * g;
    const unsigned short* wp1 = wb + ((size_t)((3 * w + 1) * 16 + q)) * DIMC + 8 * g;
    const unsigned short* wp2 = wb + ((size_t)((3 * w + 2) * 16 + q)) * DIMC + 8 * g;

    const int rl = l >> 3;                    // 0..7 row-in-call
    const int cb = (l & 7) ^ rl;              // source col-block (involution)
    const float* xsrc0 = x + (size_t)(t0 + 16 * w + 0 + rl) * DIMC + 4 * cb;
    const float* xsrc1 = x + (size_t)(t0 + 16 * w + 8 + rl) * DIMC + 4 * cb;
    unsigned char* xdst0 = xlds + (16 * w + 0) * 128;   // wave-uniform bases
    unsigned char* xdst1 = xlds + (16 * w + 8) * 128;

#define STAGE_X(bufsel, k0) do {                                              \
        async_copy16(xdst0 + (bufsel) * 8192, xsrc0 + (k0));                  \
        async_copy16(xdst1 + (bufsel) * 8192, xsrc1 + (k0));                  \
    } while (0)

    STAGE_X(0, 0);
    __syncthreads();

    int cur = 0;
    for (int it = 0; it < 16; ++it) {
        const int k0 = it << 5;
        if (it < 15) STAGE_X(cur ^ 1, k0 + 32);

        short8v wf0 = *(const short8v*)(wp0 + k0);
        short8v wf1 = *(const short8v*)(wp1 + k0);
        short8v wf2 = *(const short8v*)(wp2 + k0);

        const unsigned char* xb = xlds + cur * 8192;
        #pragma unroll
        for (int tt = 0; tt < 4; ++tt) {
            const int rr = tt * 16 + q;
            const int s0 = (2 * g)     ^ (q & 7);
            const int s1 = (2 * g + 1) ^ (q & 7);
            float4 f0 = *(const float4*)(xb + rr * 128 + s0 * 16);
            float4 f1 = *(const float4*)(xb + rr * 128 + s1 * 16);
            bfrag xv;
            xv.u[0] = packbf(f0.x, f0.y); xv.u[1] = packbf(f0.z, f0.w);
            xv.u[2] = packbf(f1.x, f1.y); xv.u[3] = packbf(f1.z, f1.w);
            acc[0][tt] = __builtin_amdgcn_mfma_f32_16x16x32_bf16(wf0, xv.v, acc[0][tt], 0, 0, 0);
            acc[1][tt] = __builtin_amdgcn_mfma_f32_16x16x32_bf16(wf1, xv.v, acc[1][tt], 0, 0, 0);
            acc[2][tt] = __builtin_amdgcn_mfma_f32_16x16x32_bf16(wf2, xv.v, acc[2][tt], 0, 0, 0);
        }

        __syncthreads();                      // nxt resident; cur reads done
        cur ^= 1;
    }

    const float qscale = 1.4426950408889634f / 22.627416997969522f; // log2e/sqrt(512)
    #pragma unroll
    for (int j = 0; j < 3; ++j) {
        const int gt   = 3 * w + j;           // global h-tile 0..11
        const int mat  = gt >> 2;             // 0=q, 1=k, 2=v
        const int hbase = (gt & 3) * 16 + 4 * g;
        #pragma unroll
        for (int tt = 0; tt < 4; ++tt) {
            const int trow = t0 + tt * 16 + q;
            const int tl   = trow & (TT - 1);
            if (mat == 2) {
                const int b = trow >> 11;
                #pragma unroll
                for (int r = 0; r < 4; ++r)
                    vt[((size_t)(b * HEADH) + hbase + r) * TT + tl] = f2bf(acc[j][tt][r]);
            } else {
                const float sc = (mat == 0) ? qscale : 1.f;
                unsigned short* dst = ((mat == 0) ? qo : ko) + (size_t)trow * HEADH;
                const int half = hbase >> 5;
                const float* frt = half ? fyr : fxr;
                const float* fit = half ? fyi : fxi;
                const int pi0 = (hbase & 31) >> 1;
                float fr0 = frt[tl * 16 + pi0],     fi0 = fit[tl * 16 + pi0];
                float fr1 = frt[tl * 16 + pi0 + 1], fi1 = fit[tl * 16 + pi0 + 1];
                float e0 = acc[j][tt][0] * fr0 - acc[j][tt][1] * fi0;
                float e1 = acc[j][tt][0] * fi0 + acc[j][tt][1] * fr0;
                float e2 = acc[j][tt][2] * fr1 - acc[j][tt][3] * fi1;
                float e3 = acc[j][tt][2] * fi1 + acc[j][tt][3] * fr1;
                uint2 ow;
                ow.x = packbf(e0 * sc, e1 * sc);
                ow.y = packbf(e2 * sc, e3 * sc);
                *(uint2*)(dst + hbase) = ow;
            }
        }
    }
#undef STAGE_X
}

// ---------------- Kernel B: MFMA flash attention, 16-wave q-tile-128 --------
// Round 17: r14's verified 16x16 inner loop, q-tile per block 64 -> 128.
// Block = 1024 thr = 16 waves: wq = w&7 (8 q-subtiles of 16 rows), h = w>>3
// (kv half, 1024 rows, 16 iters of KVBLK=64). Halves per-batch K/V L2
// traffic (256 -> 128 MB) and raises occupancy (16 waves/CU). Each of the
// 8 waves of a half stages 8 rows of K and 8 d-rows of V (1 call each).
// LDS 96KB: K[2h][2buf][64][128B] 32K | V same 32K | plds 16x2KB 32K.
// End: 2-way combine over 128 rows (r12-verified math).
__global__ __launch_bounds__(1024, 4) void attn_mfma_kernel(
    const unsigned short* __restrict__ qws,   // [b][t][64] bf16, pre-scaled
    const unsigned short* __restrict__ kws,   // [b][t][64] bf16
    const unsigned short* __restrict__ vtw,   // [b][d][t]  bf16 (V^T)
    float* __restrict__ out)
{
    __shared__ unsigned char smem[98304];

    const int tid = threadIdx.x;
    const int w   = tid >> 6;                 // 0..15
    const int wq  = w & 7;                    // q-subtile
    const int h   = w >> 3;                   // kv half
    const int l   = tid & 63;
    const int q   = l & 15;
    const int g   = l >> 4;
    const int b   = blockIdx.x >> 4;
    const int q0  = (blockIdx.x & 15) << 7;   // 128 q-rows per block
    const int qw  = q0 + 16 * wq;             // this wave's q base
    const int rx  = q & 7;                    // read-side swizzle
    const int swz = (q & 7) << 2;             // plds swizzle (verified r2-r14)

    const int rl = l >> 3;
    const int sl = (l & 7) ^ rl;              // involution pre-swizzle

    unsigned int* pldsw = (unsigned int*)(smem + 65536 + (w << 11));

    const unsigned short* kbase = kws + (size_t)b * TT * HEADH;
    const unsigned short* vbase = vtw + (size_t)b * HEADH * TT;

    // K: half's rows h*1024 + kv0 + [0,64); wave wq stages rows 8wq..8wq+7
    const unsigned short* ksrc = kbase + (size_t)(h * 1024 + 8 * wq + rl) * HEADH + 8 * sl;
    // V^T: d-rows 8wq..8wq+7, t-cols h*1024 + kv0 + [0,64)
    const unsigned short* vsrc = vbase + (size_t)(8 * wq + rl) * TT + h * 1024 + 8 * sl;

#define STAGE_TILE(bufsel, kv)  do {                                          \
        unsigned char* kd = smem + (h << 14) + (bufsel) * 8192 + (wq << 10);  \
        async_copy16(kd, ksrc + (size_t)(kv) * HEADH);                        \
        unsigned char* vd = smem + 32768 + (h << 14) + (bufsel) * 8192 + (wq << 10); \
        async_copy16(vd, vsrc + (kv));                                        \
    } while (0)

    short8v qf0, qf1;
    {
        const unsigned short* qp = qws + ((size_t)(b * TT + qw + q)) * HEADH + 8 * g;
        qf0 = *(const short8v*)(qp);
        qf1 = *(const short8v*)(qp + 32);
    }

    f32x4 oacc[4];
    #pragma unroll
    for (int mt = 0; mt < 4; ++mt) oacc[mt] = (f32x4){0.f, 0.f, 0.f, 0.f};
    float m = -1e30f, lsum = 0.f;

    STAGE_TILE(0, 0);
    __syncthreads();                          // tile 0 resident

    int cur = 0;
    for (int it = 0; it < 16; ++it) {
        const int kv0 = it << 6;              // offset within this half
        if (it < 15) STAGE_TILE(cur ^ 1, kv0 + 64);

        const unsigned char* kb = smem + (h << 14) + cur * 8192;
        const unsigned char* vb = smem + 32768 + (h << 14) + cur * 8192;

        // ---- QK^T from LDS ----
        f32x4 sacc[4];
        #pragma unroll
        for (int n = 0; n < 4; ++n) {
            const int r = 16 * n + q;
            const short8v k0 = *(const short8v*)(kb + r * 128 + ((g ^ rx) << 4));
            const short8v k1 = *(const short8v*)(kb + r * 128 + (((4 + g) ^ rx) << 4));
            f32x4 z = (f32x4){0.f, 0.f, 0.f, 0.f};
            z = __builtin_amdgcn_mfma_f32_16x16x32_bf16(k0, qf0, z, 0, 0, 0);
            z = __builtin_amdgcn_mfma_f32_16x16x32_bf16(k1, qf1, z, 0, 0, 0);
            sacc[n] = z;
        }

        // ---- online softmax (lane owns q-row qw + (l&15)) ----
        float nx[4];
        #pragma unroll
        for (int n = 0; n < 4; ++n)
            nx[n] = fmaxf(fmaxf(sacc[n][0], sacc[n][1]),
                          fmaxf(sacc[n][2], sacc[n][3]));
        float cmax = fmaxf(fmaxf(nx[0], nx[1]), fmaxf(nx[2], nx[3]));
        cmax = fmaxf(cmax, __shfl_xor(cmax, 16));
        cmax = fmaxf(cmax, __shfl_xor(cmax, 32));
        const float mnew = fmaxf(m, cmax);

        float p[4][4];
        #pragma unroll
        for (int n = 0; n < 4; ++n) {
            #pragma unroll
            for (int r = 0; r < 4; ++r)
                p[n][r] = EXP2R(sacc[n][r] - mnew);   // raw v_exp_f32
            uint2 wv;
            wv.x = packbf(p[n][0], p[n][1]);
            wv.y = packbf(p[n][2], p[n][3]);
            *(uint2*)&pldsw[q * 32 + ((8 * n + 2 * g) ^ swz)] = wv;
        }

        const float sc = EXP2R(m - mnew);
        if (__any(cmax > m)) {
            #pragma unroll
            for (int mt = 0; mt < 4; ++mt)
                #pragma unroll
                for (int r = 0; r < 4; ++r) oacc[mt][r] *= sc;
        }

        // ---- PV: out^T += V^T . P^T ----
        #pragma unroll
        for (int s = 0; s < 2; ++s) {
            const short8v pb = *(const short8v*)&pldsw[q * 32 + ((16 * s + 4 * g) ^ swz)];
            #pragma unroll
            for (int mt = 0; mt < 4; ++mt) {
                const int d = 16 * mt + q;
                const short8v vfr = *(const short8v*)(vb + d * 128 + ((((s << 2) + g) ^ rx) << 4));
                oacc[mt] = __builtin_amdgcn_mfma_f32_16x16x32_bf16(vfr, pb, oacc[mt], 0, 0, 0);
            }
        }

        // ---- psum reduce off the critical path ----
        float psum = 0.f;
        #pragma unroll
        for (int n = 0; n < 4; ++n)
            #pragma unroll
            for (int r = 0; r < 4; ++r) psum += p[n][r];
        psum += __shfl_xor(psum, 16);
        psum += __shfl_xor(psum, 32);
        lsum = lsum * sc + psum;
        m = mnew;

        __syncthreads();                      // nxt resident; cur reads done
        cur ^= 1;
    }

    // ---- 2-way combine of KV-half partials through LDS ----
    __syncthreads();                           // all staging/plds reads done
    float* o_f  = (float*)smem;                // [2][128][64] f32 = 64KB
    float* ml_f = (float*)(smem + 65536);      // [2][2][128]
    {
        const int prow = h * 128 + 16 * wq + q;
        #pragma unroll
        for (int mt = 0; mt < 4; ++mt)
            *(f32x4*)&o_f[prow * 64 + 16 * mt + 4 * g] = oacc[mt];
        if (g == 0) {
            ml_f[h * 256 + 16 * wq + q]       = m;
            ml_f[h * 256 + 128 + 16 * wq + q] = lsum;
        }
    }
    __syncthreads();

    const int cq = tid >> 3;                   // 0..127: q row
    const int ch = (tid & 7) << 3;             // 0..56: h group of 8
    const float m0 = ml_f[cq],       l0 = ml_f[128 + cq];
    const float m1 = ml_f[256 + cq], l1 = ml_f[384 + cq];
    const float M  = fmaxf(m0, m1);
    const float a0 = EXP2R(m0 - M), a1 = EXP2R(m1 - M);
    const float inv = 1.f / (a0 * l0 + a1 * l1);
    const float* o0 = &o_f[cq * 64 + ch];
    const float* o1 = &o_f[(128 + cq) * 64 + ch];
    float4 A0 = *(const float4*)(o0), B0 = *(const float4*)(o0 + 4);
    float4 A1 = *(const float4*)(o1), B1 = *(const float4*)(o1 + 4);
    float* op = out + ((size_t)(b * TT + q0 + cq)) * HEADH + ch;
    *(float4*)(op)     = make_float4((a0 * A0.x + a1 * A1.x) * inv,
                                     (a0 * A0.y + a1 * A1.y) * inv,
                                     (a0 * A0.z + a1 * A1.z) * inv,
                                     (a0 * A0.w + a1 * A1.w) * inv);
    *(float4*)(op + 4) = make_float4((a0 * B0.x + a1 * B1.x) * inv,
                                     (a0 * B0.y + a1 * B1.y) * inv,
                                     (a0 * B0.z + a1 * B1.z) * inv,
                                     (a0 * B0.w + a1 * B1.w) * inv);
#undef STAGE_TILE
}

extern "C" void kernel_launch(void* const* d_in, const int* in_sizes, int n_in,
                              void* d_out, int out_size, void* d_ws, size_t ws_size,
                              hipStream_t stream)
{
    const float* x   = (const float*)d_in[0];
    const float* Wq  = (const float*)d_in[1];
    const float* Wk  = (const float*)d_in[2];
    const float* Wv  = (const float*)d_in[3];
    const float* fxr = (const float*)d_in[4];
    const float* fxi = (const float*)d_in[5];
    const float* fyr = (const float*)d_in[6];
    const float* fyi = (const float*)d_in[7];
    float* out = (float*)d_out;

    unsigned short* qo = (unsigned short*)d_ws;                  // 4 MB
    unsigned short* ko = qo + (size_t)BB * TT * HEADH;           // 4 MB
    unsigned short* vt = ko + (size_t)BB * TT * HEADH;           // 4 MB
    unsigned short* wb = vt + (size_t)BB * TT * HEADH;           // 192 KB

    wcvt_kernel<<<48, 256, 0, stream>>>(Wq, Wk, Wv, wb);
    qkv_mfma_kernel<<<(BB * TT) / 64, 256, 0, stream>>>(x, wb, fxr, fxi, fyr, fyi,
                                                        qo, ko, vt);
    attn_mfma_kernel<<<BB * 16, 1024, 0, stream>>>(qo, ko, vt, out);
}